// Round 5
// baseline (456.995 us; speedup 1.0000x reference)
//
#include <hip/hip_runtime.h>

typedef __bf16 bf16x8 __attribute__((ext_vector_type(8)));
typedef float f32x4 __attribute__((ext_vector_type(4)));
typedef unsigned short u16x8 __attribute__((ext_vector_type(8)));
typedef unsigned short u16x4 __attribute__((ext_vector_type(4)));
typedef unsigned short u16;
typedef unsigned int u32;

// S=2048, B=2, H=1024, NH=16, HD=64, SCALE=32 (exact)
// Inputs fp32, output fp32. Internal: bf16 MFMA, fp32 accum.
// Softmax is max-free (scores tightly bounded); log2(e) folded into q gate -> exp2 direct.

#define LOG2E 1.4426950408889634f

__device__ __forceinline__ float b2f(u16 u) {
  union { unsigned int i; float f; } x; x.i = ((unsigned int)u) << 16; return x.f;
}
__device__ __forceinline__ u16 f2b(float f) {
  union { float f; unsigned int i; } x; x.f = f;
  unsigned int r = (x.i + 0x7fffu + ((x.i >> 16) & 1u)) >> 16;
  return (u16)r;
}
__device__ __forceinline__ float sigm(float x) { return 1.0f / (1.0f + __expf(-x)); }
__device__ __forceinline__ u32 cvtpk(float lo, float hi) {
  u32 r; asm("v_cvt_pk_bf16_f32 %0, %1, %2" : "=v"(r) : "v"(lo), "v"(hi)); return r;
}

__device__ __forceinline__ void async16(u16* lds, const u16* g) {
  __builtin_amdgcn_global_load_lds((const __attribute__((address_space(1))) void*)g,
                                   (__attribute__((address_space(3))) void*)lds, 16, 0, 0);
}

// ---- kernel 0: fp32->bf16 conversions (grid-stride) + h MLP + gate precompute
__global__ __launch_bounds__(256) void k_cvt_h(const float4* __restrict__ q, u16x4* __restrict__ qd,
                                               const float4* __restrict__ w, u16x4* __restrict__ wd,
                                               const float4* __restrict__ k, u16x4* __restrict__ kd,
                                               const float4* __restrict__ v, u16x4* __restrict__ vd,
                                               const float* __restrict__ vs,
                                               const float* __restrict__ vq_w,
                                               const float* __restrict__ vq_b,
                                               float* __restrict__ h,
                                               const float* __restrict__ qs,
                                               const float* __restrict__ ks,
                                               float* __restrict__ gate) {
  __shared__ float svs[1024];
  int b = blockIdx.x;
  int t = threadIdx.x;
  if (b < 2048) {
#pragma unroll
    for (int vb = b; vb < 18432; vb += 2048) {
      const float4* s; u16x4* d; int i;
      if (vb < 8192)       { s = q; d = qd; i = vb * 256 + t; }
      else if (vb < 10240) { s = w; d = wd; i = (vb - 8192) * 256 + t; }
      else if (vb < 14336) { s = k; d = kd; i = (vb - 10240) * 256 + t; }
      else                 { s = v; d = vd; i = (vb - 14336) * 256 + t; }
      float4 x = s[i];
      u16x4 o; o[0] = f2b(x.x); o[1] = f2b(x.y); o[2] = f2b(x.z); o[3] = f2b(x.w);
      d[i] = o;
    }
    return;
  }
  if (b < 2560) {
    for (int i = t; i < 1024; i += 256) svs[i] = sigm(vs[i]);
    __syncthreads();
    int wave = t >> 6, lane = t & 63;
    int row = (b - 2048) * 4 + wave;
    const float4* w4 = (const float4*)(vq_w + (size_t)row * 1024);
    const float4* s4 = (const float4*)svs;
    float acc = 0.f;
#pragma unroll
    for (int kk = 0; kk < 4; ++kk) {
      float4 wv = w4[kk * 64 + lane];
      float4 sv = s4[kk * 64 + lane];
      acc += wv.x * sv.x + wv.y * sv.y + wv.z * sv.z + wv.w * sv.w;
    }
#pragma unroll
    for (int off = 1; off < 64; off <<= 1) acc += __shfl_xor(acc, off);
    if (lane == 0) h[row] = acc + vq_b[row];
    return;
  }
  int ch = (b - 2560) * 256 + t;
  gate[ch] = sigm(qs[ch]) * sigm(ks[ch]) * (LOG2E / 32.0f);
}

// ---- kernel 3: qpre = query @ ql_w^T, split-K=2. 64x128 tiles, grid 1024.
// 2-phase pipeline: stage(kt+1 into buf^1) BEFORE compute(buf), vmcnt(0)+barrier after.
__global__ __launch_bounds__(256) void k_gemm(const u16* __restrict__ A,    // 4096 x 2048 bf16
                                              const u16* __restrict__ Bt,   // 1024 x 2048 bf16
                                              u16* __restrict__ C) {        // 2 x (4096 x 1024)
  __shared__ __align__(16) u16 As[2][64 * 32];
  __shared__ __align__(16) u16 Bs[2][128 * 32];
  int tid = threadIdx.x;
  int wave = tid >> 6, lane = tid & 63;
  int l15 = lane & 15, quad = lane >> 4;
  int bx = blockIdx.x & 511;
  int kh = blockIdx.x >> 9;
  int kofs = kh << 10;
  int m0 = (bx >> 3) * 64;
  int n0 = (bx & 7) * 128;
  int wm = (wave >> 1) * 32, wn = (wave & 1) * 64;
  f32x4 acc[2][4] = {};
  int c1 = tid, c2 = tid + 256;
  const u16* gaA = A + (size_t)(m0 + (c1 >> 2)) * 2048 + kofs + (c1 & 3) * 8;
  const u16* gb1 = Bt + (size_t)(n0 + (c1 >> 2)) * 2048 + kofs + (c1 & 3) * 8;
  const u16* gb2 = Bt + (size_t)(n0 + (c2 >> 2)) * 2048 + kofs + (c2 & 3) * 8;
  int lofs = wave * 512;
  // prologue: stage tile 0 into buf 0
  async16(As[0] + lofs, gaA);
  async16(Bs[0] + lofs, gb1); async16(Bs[0] + 2048 + lofs, gb2);
  gaA += 32; gb1 += 32; gb2 += 32;
  __syncthreads();
  for (int kt = 0; kt < 32; ++kt) {
    int cur = kt & 1;
    if (kt < 31) {
      async16(As[cur ^ 1] + lofs, gaA);
      async16(Bs[cur ^ 1] + lofs, gb1); async16(Bs[cur ^ 1] + 2048 + lofs, gb2);
      gaA += 32; gb1 += 32; gb2 += 32;
    }
    bf16x8 af[2], bfr[4];
#pragma unroll
    for (int mt = 0; mt < 2; ++mt)
      af[mt] = *(const bf16x8*)(As[cur] + (wm + mt * 16 + l15) * 32 + quad * 8);
#pragma unroll
    for (int nt = 0; nt < 4; ++nt)
      bfr[nt] = *(const bf16x8*)(Bs[cur] + (wn + nt * 16 + l15) * 32 + quad * 8);
#pragma unroll
    for (int mt = 0; mt < 2; ++mt)
#pragma unroll
      for (int nt = 0; nt < 4; ++nt)
        acc[mt][nt] = __builtin_amdgcn_mfma_f32_16x16x32_bf16(af[mt], bfr[nt], acc[mt][nt], 0, 0, 0);
    __syncthreads();
  }
  u16* Cp = C + (size_t)kh * 4096 * 1024;
#pragma unroll
  for (int mt = 0; mt < 2; ++mt) {
#pragma unroll
    for (int r = 0; r < 4; ++r) {
      int m = m0 + wm + mt * 16 + quad * 4 + r;
      u16* crow = Cp + (size_t)m * 1024 + n0 + wn + l15;
#pragma unroll
      for (int nt = 0; nt < 4; ++nt) crow[nt * 16] = f2b(acc[mt][nt][r]);
    }
  }
}

// ---- kernel 4: LN((qpre0+qpre1)+ql_b)*ln_g+ln_b, * gate -> qatt (b,h,s,hd)
__global__ __launch_bounds__(256) void k_ln(const u16* __restrict__ qpre0,
                                            const u16* __restrict__ qpre1,
                                            const float* __restrict__ ql_b,
                                            const float* __restrict__ ln_g,
                                            const float* __restrict__ ln_b,
                                            const float* __restrict__ gate,
                                            u16* __restrict__ qatt) {
  int t = threadIdx.x;
  int wave = t >> 6, lane = t & 63;
  int row = blockIdx.x * 4 + wave;     // row = s*2 + b
  int ch0 = lane * 16;
  const u16* p0 = qpre0 + (size_t)row * 1024 + ch0;
  const u16* p1 = qpre1 + (size_t)row * 1024 + ch0;
  u16x8 a0 = *(const u16x8*)p0;
  u16x8 a1 = *(const u16x8*)(p0 + 8);
  u16x8 c0 = *(const u16x8*)p1;
  u16x8 c1 = *(const u16x8*)(p1 + 8);
  float qb[16];
#pragma unroll
  for (int i = 0; i < 4; ++i) *(float4*)&qb[i * 4] = *(const float4*)(ql_b + ch0 + i * 4);
  float v[16];
  float s = 0.f, ss = 0.f;
#pragma unroll
  for (int j = 0; j < 8; ++j) {
    v[j] = b2f(a0[j]) + b2f(c0[j]) + qb[j];
    v[8 + j] = b2f(a1[j]) + b2f(c1[j]) + qb[8 + j];
  }
#pragma unroll
  for (int j = 0; j < 16; ++j) { s += v[j]; ss += v[j] * v[j]; }
#pragma unroll
  for (int off = 1; off < 64; off <<= 1) { s += __shfl_xor(s, off); ss += __shfl_xor(ss, off); }
  float mu = s * (1.f / 1024.f);
  float rstd = rsqrtf(ss * (1.f / 1024.f) - mu * mu + 1e-12f);
  float g_[16], bb[16], gt[16];
#pragma unroll
  for (int i = 0; i < 4; ++i) {
    *(float4*)&g_[i * 4] = *(const float4*)(ln_g + ch0 + i * 4);
    *(float4*)&bb[i * 4] = *(const float4*)(ln_b + ch0 + i * 4);
    *(float4*)&gt[i * 4] = *(const float4*)(gate + ch0 + i * 4);
  }
  int sidx = row >> 1, b = row & 1;
  int hh = ch0 >> 6, hd0 = ch0 & 63;
  u16* dst = qatt + ((size_t)(b * 16 + hh) * 2048 + sidx) * 64 + hd0;
  u16x8 o0, o1;
#pragma unroll
  for (int j = 0; j < 8; ++j) {
    o0[j] = f2b(((v[j] - mu) * rstd * g_[j] + bb[j]) * gt[j]);
    o1[j] = f2b(((v[8 + j] - mu) * rstd * g_[8 + j] + bb[8 + j]) * gt[8 + j]);
  }
  *(u16x8*)dst = o0;
  *(u16x8*)(dst + 8) = o1;
}

// ---- kernel 5: flash attention, swapped-QK in-register softmax, 2x2 wave split.
// wave = (qh, kh): 64 queries x 32 keys per wave -> LDS reads per wave per tile HALVED
// (4 K b128 + 4 V b128). PV is one K=32 MFMA per (qfrag, ch-group). Cross-pair O
// reduction through LDS (reusing K/V buffers) once at the end.
__device__ __forceinline__ f32x4 mfma16(bf16x8 a, bf16x8 b, f32x4 c) {
  return __builtin_amdgcn_mfma_f32_16x16x32_bf16(a, b, c, 0, 0, 0);
}

template <int CUR>
__device__ __forceinline__ void attn_iter(bool pref,
                                          const bf16x8 (&qf)[4][2],
                                          const u16*& kp, const u16*& vp,
                                          u16 (&Ks)[2][64 * 64], u16 (&Vt)[2][64 * 64],
                                          f32x4 (&oacc)[4][4], float (&l_i)[4],
                                          int kdst, int chbase, int pcol,
                                          int l15, int kh, int kcolA, int kcolB, int vcol) {
  // QK^T swapped: K A-frags (this wave's 32 keys) from swizzled LDS.
  // sacc[f][kn]: lane = S[key = kh*32 + kn*16 + quad*4 + r][qrow = l15 of qfrag f]
  const u16* kt0 = Ks[CUR] + (kh * 32 + l15) * 64;
  bf16x8 kA0 = *(const bf16x8*)(kt0 + kcolA);
  bf16x8 kB0 = *(const bf16x8*)(kt0 + kcolB);
  bf16x8 kA1 = *(const bf16x8*)(kt0 + 16 * 64 + kcolA);
  bf16x8 kB1 = *(const bf16x8*)(kt0 + 16 * 64 + kcolB);
  f32x4 sacc[4][2] = {};
  __builtin_amdgcn_s_setprio(1);
#pragma unroll
  for (int f = 0; f < 4; ++f) {
    sacc[f][0] = mfma16(kA0, qf[f][0], sacc[f][0]);
    sacc[f][0] = mfma16(kB0, qf[f][1], sacc[f][0]);
    sacc[f][1] = mfma16(kA1, qf[f][0], sacc[f][1]);
    sacc[f][1] = mfma16(kB1, qf[f][1], sacc[f][1]);
  }
  __builtin_amdgcn_s_setprio(0);
  // prefetch K(kt+1), V(kt+1) rows into registers (coalesced, 2+2 x 16B per thread)
  u16x8 kr0, kr1, va, vq;
  if (pref) {
    kp += 64 * 2048;
    kr0 = *(const u16x8*)kp;
    kr1 = *(const u16x8*)(kp + (size_t)32 * 2048);
    vp += 64 * 2048;
    va = *(const u16x8*)vp;
    vq = *(const u16x8*)(vp + 2048);
  }
  // softmax: p = 2^s; pack to bf16 A-frag (j = kn*4 + r matches pi_local V order)
  union U8 { u32 w[4]; bf16x8 v; };
  bf16x8 pa[4];
#pragma unroll
  for (int f = 0; f < 4; ++f) {
    float pe[2][4];
#pragma unroll
    for (int kn = 0; kn < 2; ++kn)
#pragma unroll
      for (int r = 0; r < 4; ++r) pe[kn][r] = __builtin_amdgcn_exp2f(sacc[f][kn][r]);
    l_i[f] += (pe[0][0] + pe[0][1] + pe[0][2] + pe[0][3]) +
              (pe[1][0] + pe[1][1] + pe[1][2] + pe[1][3]);
    U8 t;
    t.w[0] = cvtpk(pe[0][0], pe[0][1]); t.w[1] = cvtpk(pe[0][2], pe[0][3]);
    t.w[2] = cvtpk(pe[1][0], pe[1][1]); t.w[3] = cvtpk(pe[1][2], pe[1][3]);
    pa[f] = t.v;
  }
  // PV: one K=32 MFMA per (qfrag, ch-group); V B-frag from this wave's key-half cols
  const u16* vt0 = Vt[CUR];
  __builtin_amdgcn_s_setprio(1);
#pragma unroll
  for (int nt = 0; nt < 4; ++nt) {
    bf16x8 vF = *(const bf16x8*)(vt0 + (nt * 16 + l15) * 64 + vcol);
    oacc[0][nt] = mfma16(pa[0], vF, oacc[0][nt]);
    oacc[1][nt] = mfma16(pa[1], vF, oacc[1][nt]);
    oacc[2][nt] = mfma16(pa[2], vF, oacc[2][nt]);
    oacc[3][nt] = mfma16(pa[3], vF, oacc[3][nt]);
  }
  __builtin_amdgcn_s_setprio(0);
  // stage K(kt+1), V(kt+1) into other buffer (readers finished at previous barrier)
  if (pref) {
    u16* kd = (u16*)Ks[CUR ^ 1];
    *(u16x8*)(kd + kdst) = kr0;
    *(u16x8*)(kd + kdst + 2048) = kr1;
    u16* vd = (u16*)Vt[CUR ^ 1];
#pragma unroll
    for (int c = 0; c < 8; ++c) {
      u32 pk2 = (u32)va[c] | ((u32)vq[c] << 16);
      *(u32*)&vd[(chbase + c) * 64 + (pcol ^ (c << 3))] = pk2;
    }
  }
  __syncthreads();
}

__global__ __launch_bounds__(256, 2) void k_attn(const u16* __restrict__ qatt,
                                                 const u16* __restrict__ key,
                                                 const u16* __restrict__ value,
                                                 const float* __restrict__ hbuf,
                                                 float* __restrict__ out) {
  int bh = blockIdx.x & 31;
  int qt = blockIdx.x >> 5;
  int b = bh >> 4, h = bh & 15;
  int tid = threadIdx.x, wave = tid >> 6, lane = tid & 63;
  int l15 = lane & 15, quad = lane >> 4;
  int qh = wave >> 1, kh = wave & 1;
  int q0 = qt * 128;

  __shared__ __align__(16) u16 Ks[2][64 * 64];   // [buf][key][ch], XOR-swizzled 128B rows
  __shared__ __align__(16) u16 Vt[2][64 * 64];   // [buf][ch][pi(key)], XOR-swizzled 128B rows
  __shared__ float Lx[2][2][32];                 // [qh][half][qlocal] l partials

  // Q B-frags: 4 qfrags x 2 ch-chunks; qrow = q0 + qh*64 + f*16 + l15
  bf16x8 qf[4][2];
#pragma unroll
  for (int f = 0; f < 4; ++f) {
    const u16* qrow = qatt + ((size_t)bh * 2048 + q0 + qh * 64 + f * 16 + l15) * 64 + quad * 8;
    qf[f][0] = *(const bf16x8*)qrow;
    qf[f][1] = *(const bf16x8*)(qrow + 32);
  }

  const u16* kb = key + (size_t)b * 1024 + (size_t)h * 64;
  const u16* vb = value + (size_t)b * 1024 + (size_t)h * 64;

  // K staging: thread t covers rows {t>>3, 32+(t>>3)}, ch chunk (t&7)*8
  int krow = tid >> 3;
  int kchk = (tid & 7) * 8;
  const u16* kp = kb + (size_t)krow * 2048 + kchk;
  int kdst = krow * 64 + (kchk ^ ((krow & 7) << 3));

  // V staging: lane covers keys 2p,2p+1 (p=lane&31), 8 ch at chbase; scatter col = pi(2p)
  int p = lane & 31;
  int chbase = wave * 16 + (lane >> 5) * 8;
  const u16* vp = vb + (size_t)2 * p * 2048 + chbase;
  int kk = 2 * p;
  int pcol = ((kk >> 5) & 1) * 32 + ((kk >> 2) & 3) * 8 + ((kk >> 4) & 1) * 4 + (kk & 3);
  int swr = (l15 & 7) << 3;                 // read-side row swizzle (u16 units)
  int kcolA = (8 * quad) ^ swr;             // K ch-chunk 0
  int kcolB = (32 + 8 * quad) ^ swr;        // K ch-chunk 1
  int vcol = (kh * 32 + 8 * quad) ^ swr;    // V key-half cols

  // prologue: K(0) into Ks[0], V(0) into Vt[0]
  {
    u16x8 kr0 = *(const u16x8*)kp;
    u16x8 kr1 = *(const u16x8*)(kp + (size_t)32 * 2048);
    *(u16x8*)(&Ks[0][kdst]) = kr0;
    *(u16x8*)(&Ks[0][kdst + 2048]) = kr1;
    u16x8 va = *(const u16x8*)vp;
    u16x8 vq = *(const u16x8*)(vp + 2048);
#pragma unroll
    for (int c = 0; c < 8; ++c) {
      u32 pk2 = (u32)va[c] | ((u32)vq[c] << 16);
      *(u32*)&Vt[0][(chbase + c) * 64 + (pcol ^ (c << 3))] = pk2;
    }
  }
  __syncthreads();

  f32x4 oacc[4][4] = {};
  float l_i[4] = {};

  for (int kt = 0; kt < 32; kt += 2) {
    attn_iter<0>(true, qf, kp, vp, Ks, Vt, oacc, l_i, kdst, chbase, pcol, l15, kh, kcolA, kcolB, vcol);
    attn_iter<1>(kt < 30, qf, kp, vp, Ks, Vt, oacc, l_i, kdst, chbase, pcol, l15, kh, kcolA, kcolB, vcol);
  }

  // quad-reduce l (lane holds partial for qrow=l15 over this wave's keys)
#pragma unroll
  for (int f = 0; f < 4; ++f) {
    float l = l_i[f];
    l += __shfl_xor(l, 16);
    l += __shfl_xor(l, 32);
    l_i[f] = l;
  }
  // cross-pair O reduction: wave (qh,kh) donates q-half d=kh^1 to LDS, keeps half kh.
  int d = kh ^ 1;
  float* base = (qh == 0) ? (float*)&Ks[0][0] : (float*)&Vt[0][0];
  float* Rw = base + d * 2048;
#pragma unroll
  for (int ff = 0; ff < 2; ++ff) {
    int fo = d * 2 + ff;
#pragma unroll
    for (int nt = 0; nt < 4; ++nt)
#pragma unroll
      for (int r = 0; r < 4; ++r)
        Rw[(ff * 16 + quad * 4 + r) * 64 + nt * 16 + l15] = oacc[fo][nt][r];
    if (quad == 0) Lx[qh][d][ff * 16 + l15] = l_i[fo];
  }
  __syncthreads();
  // vsig inline (h holds MLP pre-activations: c = h[ch], f = h[1024+ch])
  float vsg[4];
#pragma unroll
  for (int nt = 0; nt < 4; ++nt) {
    int ch = h * 64 + nt * 16 + l15;
    vsg[nt] = sigm(hbuf[1024 + ch]) * tanhf(hbuf[ch]);
  }
  // epilogue: own half = partner's donated region + own oacc; /l, *vsig, write (s,b,H) fp32
  float* Rr = base + kh * 2048;
#pragma unroll
  for (int ff = 0; ff < 2; ++ff) {
    int fo = kh * 2 + ff;
    float lt = l_i[fo] + Lx[qh][kh][ff * 16 + l15];
#pragma unroll
    for (int r = 0; r < 4; ++r) {
      int sq = q0 + qh * 64 + kh * 32 + ff * 16 + quad * 4 + r;
      float inv = 1.0f / __shfl(lt, quad * 4 + r);
      float* orow = out + ((size_t)sq * 2 + b) * 1024 + h * 64;
#pragma unroll
      for (int nt = 0; nt < 4; ++nt)
        orow[nt * 16 + l15] =
            (oacc[fo][nt][r] + Rr[(ff * 16 + quad * 4 + r) * 64 + nt * 16 + l15]) * inv * vsg[nt];
    }
  }
}

extern "C" void kernel_launch(void* const* d_in, const int* in_sizes, int n_in,
                              void* d_out, int out_size, void* d_ws, size_t ws_size,
                              hipStream_t stream) {
  (void)in_sizes; (void)n_in; (void)out_size; (void)ws_size;
  const float* query = (const float*)d_in[0];
  const float* key   = (const float*)d_in[1];
  const float* value = (const float*)d_in[2];
  const float* qs    = (const float*)d_in[3];
  const float* ksp   = (const float*)d_in[4];
  const float* vs    = (const float*)d_in[5];
  const float* vq_w  = (const float*)d_in[6];
  const float* vq_b  = (const float*)d_in[7];
  const float* ql_w  = (const float*)d_in[8];
  const float* ql_b  = (const float*)d_in[9];
  const float* ln_g  = (const float*)d_in[10];
  const float* ln_b  = (const float*)d_in[11];
  float* out = (float*)d_out;

  float* ws = (float*)d_ws;
  float* h    = ws;                                 // 2048 f32
  float* gate = ws + 2048;                          // 1024 f32
  u16* qpre  = (u16*)(ws + 4096);                   // 2 x 4096x1024 bf16 (16 MB)
  u16* qbf   = qpre + (size_t)2 * 4096 * 1024;      // query bf16 (16 MB); qatt aliases
  u16* qatt  = qbf;                                 // 32x2048x64 bf16 (ln writes after gemm reads)
  u16* wbf   = qbf + (size_t)4096 * 2048;           // ql_w bf16 (4 MB)
  u16* kbf   = wbf + (size_t)1024 * 2048;           // key bf16 (8 MB)
  u16* vbf   = kbf + (size_t)4096 * 1024;           // value bf16 (8 MB)

  hipLaunchKernelGGL(k_cvt_h, dim3(2564), dim3(256), 0, stream,
                     (const float4*)query, (u16x4*)qbf,
                     (const float4*)ql_w,  (u16x4*)wbf,
                     (const float4*)key,   (u16x4*)kbf,
                     (const float4*)value, (u16x4*)vbf,
                     vs, vq_w, vq_b, h, qs, ksp, gate);
  hipLaunchKernelGGL(k_gemm, dim3(1024), dim3(256), 0, stream, qbf, wbf, qpre);
  hipLaunchKernelGGL(k_ln,   dim3(1024), dim3(256), 0, stream, qpre, qpre + (size_t)4096 * 1024,
                     ql_b, ln_g, ln_b, gate, qatt);
  hipLaunchKernelGGL(k_attn, dim3(512),  dim3(256), 0, stream, qatt, kbf, vbf, h, out);
}

// Round 6
// 218.498 us; speedup vs baseline: 2.0915x; 2.0915x over previous
//
#include <hip/hip_runtime.h>

typedef __bf16 bf16x8 __attribute__((ext_vector_type(8)));
typedef float f32x4 __attribute__((ext_vector_type(4)));
typedef unsigned short u16x8 __attribute__((ext_vector_type(8)));
typedef unsigned short u16x4 __attribute__((ext_vector_type(4)));
typedef unsigned short u16;
typedef unsigned int u32;

// S=2048, B=2, H=1024, NH=16, HD=64, SCALE=32 (exact)
// Inputs fp32, output fp32. Internal: bf16 MFMA, fp32 accum.
// Softmax is max-free (scores tightly bounded); log2(e) folded into q gate -> exp2 direct.

#define LOG2E 1.4426950408889634f

__device__ __forceinline__ float b2f(u16 u) {
  union { unsigned int i; float f; } x; x.i = ((unsigned int)u) << 16; return x.f;
}
__device__ __forceinline__ u16 f2b(float f) {
  union { float f; unsigned int i; } x; x.f = f;
  unsigned int r = (x.i + 0x7fffu + ((x.i >> 16) & 1u)) >> 16;
  return (u16)r;
}
__device__ __forceinline__ float sigm(float x) { return 1.0f / (1.0f + __expf(-x)); }
__device__ __forceinline__ u32 cvtpk(float lo, float hi) {
  u32 r; asm("v_cvt_pk_bf16_f32 %0, %1, %2" : "=v"(r) : "v"(lo), "v"(hi)); return r;
}

__device__ __forceinline__ void async16(u16* lds, const u16* g) {
  __builtin_amdgcn_global_load_lds((const __attribute__((address_space(1))) void*)g,
                                   (__attribute__((address_space(3))) void*)lds, 16, 0, 0);
}

// ---- kernel 0: fp32->bf16 conversions (grid-stride) + h MLP + gate precompute
__global__ __launch_bounds__(256) void k_cvt_h(const float4* __restrict__ q, u16x4* __restrict__ qd,
                                               const float4* __restrict__ w, u16x4* __restrict__ wd,
                                               const float4* __restrict__ k, u16x4* __restrict__ kd,
                                               const float4* __restrict__ v, u16x4* __restrict__ vd,
                                               const float* __restrict__ vs,
                                               const float* __restrict__ vq_w,
                                               const float* __restrict__ vq_b,
                                               float* __restrict__ h,
                                               const float* __restrict__ qs,
                                               const float* __restrict__ ks,
                                               float* __restrict__ gate) {
  __shared__ float svs[1024];
  int b = blockIdx.x;
  int t = threadIdx.x;
  if (b < 2048) {
#pragma unroll
    for (int vb = b; vb < 18432; vb += 2048) {
      const float4* s; u16x4* d; int i;
      if (vb < 8192)       { s = q; d = qd; i = vb * 256 + t; }
      else if (vb < 10240) { s = w; d = wd; i = (vb - 8192) * 256 + t; }
      else if (vb < 14336) { s = k; d = kd; i = (vb - 10240) * 256 + t; }
      else                 { s = v; d = vd; i = (vb - 14336) * 256 + t; }
      float4 x = s[i];
      u16x4 o; o[0] = f2b(x.x); o[1] = f2b(x.y); o[2] = f2b(x.z); o[3] = f2b(x.w);
      d[i] = o;
    }
    return;
  }
  if (b < 2560) {
    for (int i = t; i < 1024; i += 256) svs[i] = sigm(vs[i]);
    __syncthreads();
    int wave = t >> 6, lane = t & 63;
    int row = (b - 2048) * 4 + wave;
    const float4* w4 = (const float4*)(vq_w + (size_t)row * 1024);
    const float4* s4 = (const float4*)svs;
    float acc = 0.f;
#pragma unroll
    for (int kk = 0; kk < 4; ++kk) {
      float4 wv = w4[kk * 64 + lane];
      float4 sv = s4[kk * 64 + lane];
      acc += wv.x * sv.x + wv.y * sv.y + wv.z * sv.z + wv.w * sv.w;
    }
#pragma unroll
    for (int off = 1; off < 64; off <<= 1) acc += __shfl_xor(acc, off);
    if (lane == 0) h[row] = acc + vq_b[row];
    return;
  }
  int ch = (b - 2560) * 256 + t;
  gate[ch] = sigm(qs[ch]) * sigm(ks[ch]) * (LOG2E / 32.0f);
}

// ---- kernel 3: qpre = query @ ql_w^T, split-K=2. 64x128 tiles, grid 1024.
// 2-phase pipeline: stage(kt+1 into buf^1) BEFORE compute(buf), vmcnt(0)+barrier after.
__global__ __launch_bounds__(256) void k_gemm(const u16* __restrict__ A,    // 4096 x 2048 bf16
                                              const u16* __restrict__ Bt,   // 1024 x 2048 bf16
                                              u16* __restrict__ C) {        // 2 x (4096 x 1024)
  __shared__ __align__(16) u16 As[2][64 * 32];
  __shared__ __align__(16) u16 Bs[2][128 * 32];
  int tid = threadIdx.x;
  int wave = tid >> 6, lane = tid & 63;
  int l15 = lane & 15, quad = lane >> 4;
  int bx = blockIdx.x & 511;
  int kh = blockIdx.x >> 9;
  int kofs = kh << 10;
  int m0 = (bx >> 3) * 64;
  int n0 = (bx & 7) * 128;
  int wm = (wave >> 1) * 32, wn = (wave & 1) * 64;
  f32x4 acc[2][4] = {};
  int c1 = tid, c2 = tid + 256;
  const u16* gaA = A + (size_t)(m0 + (c1 >> 2)) * 2048 + kofs + (c1 & 3) * 8;
  const u16* gb1 = Bt + (size_t)(n0 + (c1 >> 2)) * 2048 + kofs + (c1 & 3) * 8;
  const u16* gb2 = Bt + (size_t)(n0 + (c2 >> 2)) * 2048 + kofs + (c2 & 3) * 8;
  int lofs = wave * 512;
  // prologue: stage tile 0 into buf 0
  async16(As[0] + lofs, gaA);
  async16(Bs[0] + lofs, gb1); async16(Bs[0] + 2048 + lofs, gb2);
  gaA += 32; gb1 += 32; gb2 += 32;
  __syncthreads();
  for (int kt = 0; kt < 32; ++kt) {
    int cur = kt & 1;
    if (kt < 31) {
      async16(As[cur ^ 1] + lofs, gaA);
      async16(Bs[cur ^ 1] + lofs, gb1); async16(Bs[cur ^ 1] + 2048 + lofs, gb2);
      gaA += 32; gb1 += 32; gb2 += 32;
    }
    bf16x8 af[2], bfr[4];
#pragma unroll
    for (int mt = 0; mt < 2; ++mt)
      af[mt] = *(const bf16x8*)(As[cur] + (wm + mt * 16 + l15) * 32 + quad * 8);
#pragma unroll
    for (int nt = 0; nt < 4; ++nt)
      bfr[nt] = *(const bf16x8*)(Bs[cur] + (wn + nt * 16 + l15) * 32 + quad * 8);
#pragma unroll
    for (int mt = 0; mt < 2; ++mt)
#pragma unroll
      for (int nt = 0; nt < 4; ++nt)
        acc[mt][nt] = __builtin_amdgcn_mfma_f32_16x16x32_bf16(af[mt], bfr[nt], acc[mt][nt], 0, 0, 0);
    __syncthreads();
  }
  u16* Cp = C + (size_t)kh * 4096 * 1024;
#pragma unroll
  for (int mt = 0; mt < 2; ++mt) {
#pragma unroll
    for (int r = 0; r < 4; ++r) {
      int m = m0 + wm + mt * 16 + quad * 4 + r;
      u16* crow = Cp + (size_t)m * 1024 + n0 + wn + l15;
#pragma unroll
      for (int nt = 0; nt < 4; ++nt) crow[nt * 16] = f2b(acc[mt][nt][r]);
    }
  }
}

// ---- kernel 4: LN((qpre0+qpre1)+ql_b)*ln_g+ln_b, * gate -> qatt (b,h,s,hd)
__global__ __launch_bounds__(256) void k_ln(const u16* __restrict__ qpre0,
                                            const u16* __restrict__ qpre1,
                                            const float* __restrict__ ql_b,
                                            const float* __restrict__ ln_g,
                                            const float* __restrict__ ln_b,
                                            const float* __restrict__ gate,
                                            u16* __restrict__ qatt) {
  int t = threadIdx.x;
  int wave = t >> 6, lane = t & 63;
  int row = blockIdx.x * 4 + wave;     // row = s*2 + b
  int ch0 = lane * 16;
  const u16* p0 = qpre0 + (size_t)row * 1024 + ch0;
  const u16* p1 = qpre1 + (size_t)row * 1024 + ch0;
  u16x8 a0 = *(const u16x8*)p0;
  u16x8 a1 = *(const u16x8*)(p0 + 8);
  u16x8 c0 = *(const u16x8*)p1;
  u16x8 c1 = *(const u16x8*)(p1 + 8);
  float qb[16];
#pragma unroll
  for (int i = 0; i < 4; ++i) *(float4*)&qb[i * 4] = *(const float4*)(ql_b + ch0 + i * 4);
  float v[16];
  float s = 0.f, ss = 0.f;
#pragma unroll
  for (int j = 0; j < 8; ++j) {
    v[j] = b2f(a0[j]) + b2f(c0[j]) + qb[j];
    v[8 + j] = b2f(a1[j]) + b2f(c1[j]) + qb[8 + j];
  }
#pragma unroll
  for (int j = 0; j < 16; ++j) { s += v[j]; ss += v[j] * v[j]; }
#pragma unroll
  for (int off = 1; off < 64; off <<= 1) { s += __shfl_xor(s, off); ss += __shfl_xor(ss, off); }
  float mu = s * (1.f / 1024.f);
  float rstd = rsqrtf(ss * (1.f / 1024.f) - mu * mu + 1e-12f);
  float g_[16], bb[16], gt[16];
#pragma unroll
  for (int i = 0; i < 4; ++i) {
    *(float4*)&g_[i * 4] = *(const float4*)(ln_g + ch0 + i * 4);
    *(float4*)&bb[i * 4] = *(const float4*)(ln_b + ch0 + i * 4);
    *(float4*)&gt[i * 4] = *(const float4*)(gate + ch0 + i * 4);
  }
  int sidx = row >> 1, b = row & 1;
  int hh = ch0 >> 6, hd0 = ch0 & 63;
  u16* dst = qatt + ((size_t)(b * 16 + hh) * 2048 + sidx) * 64 + hd0;
  u16x8 o0, o1;
#pragma unroll
  for (int j = 0; j < 8; ++j) {
    o0[j] = f2b(((v[j] - mu) * rstd * g_[j] + bb[j]) * gt[j]);
    o1[j] = f2b(((v[8 + j] - mu) * rstd * g_[8 + j] + bb[8 + j]) * gt[8 + j]);
  }
  *(u16x8*)dst = o0;
  *(u16x8*)(dst + 8) = o1;
}

// ---- kernel 5: flash attention, swapped-QK in-register softmax, 2x2 wave split.
// wave = (qh, kh): 64 queries x 32 keys per wave -> LDS reads per wave per tile HALVED.
// Epilogue cross-pair O reduction uses WAVE-UNIFORM branches on kh with STATIC oacc
// indices (rule #20: runtime-indexed ext_vector arrays spill to scratch -- R5 bug).
__device__ __forceinline__ f32x4 mfma16(bf16x8 a, bf16x8 b, f32x4 c) {
  return __builtin_amdgcn_mfma_f32_16x16x32_bf16(a, b, c, 0, 0, 0);
}

template <int CUR>
__device__ __forceinline__ void attn_iter(bool pref,
                                          const bf16x8 (&qf)[4][2],
                                          const u16*& kp, const u16*& vp,
                                          u16 (&Ks)[2][64 * 64], u16 (&Vt)[2][64 * 64],
                                          f32x4 (&oacc)[4][4], float (&l_i)[4],
                                          int kdst, int chbase, int pcol,
                                          int l15, int kh, int kcolA, int kcolB, int vcol) {
  // QK^T swapped: K A-frags (this wave's 32 keys) from swizzled LDS.
  // sacc[f][kn]: lane = S[key = kh*32 + kn*16 + quad*4 + r][qrow = l15 of qfrag f]
  const u16* kt0 = Ks[CUR] + (kh * 32 + l15) * 64;
  bf16x8 kA0 = *(const bf16x8*)(kt0 + kcolA);
  bf16x8 kB0 = *(const bf16x8*)(kt0 + kcolB);
  bf16x8 kA1 = *(const bf16x8*)(kt0 + 16 * 64 + kcolA);
  bf16x8 kB1 = *(const bf16x8*)(kt0 + 16 * 64 + kcolB);
  f32x4 sacc[4][2] = {};
  __builtin_amdgcn_s_setprio(1);
#pragma unroll
  for (int f = 0; f < 4; ++f) {
    sacc[f][0] = mfma16(kA0, qf[f][0], sacc[f][0]);
    sacc[f][0] = mfma16(kB0, qf[f][1], sacc[f][0]);
    sacc[f][1] = mfma16(kA1, qf[f][0], sacc[f][1]);
    sacc[f][1] = mfma16(kB1, qf[f][1], sacc[f][1]);
  }
  __builtin_amdgcn_s_setprio(0);
  // prefetch K(kt+1), V(kt+1) rows into registers (coalesced, 2+2 x 16B per thread)
  u16x8 kr0, kr1, va, vq;
  if (pref) {
    kp += 64 * 2048;
    kr0 = *(const u16x8*)kp;
    kr1 = *(const u16x8*)(kp + (size_t)32 * 2048);
    vp += 64 * 2048;
    va = *(const u16x8*)vp;
    vq = *(const u16x8*)(vp + 2048);
  }
  // softmax: p = 2^s; pack to bf16 A-frag (j = kn*4 + r matches pi_local V order)
  union U8 { u32 w[4]; bf16x8 v; };
  bf16x8 pa[4];
#pragma unroll
  for (int f = 0; f < 4; ++f) {
    float pe[2][4];
#pragma unroll
    for (int kn = 0; kn < 2; ++kn)
#pragma unroll
      for (int r = 0; r < 4; ++r) pe[kn][r] = __builtin_amdgcn_exp2f(sacc[f][kn][r]);
    l_i[f] += (pe[0][0] + pe[0][1] + pe[0][2] + pe[0][3]) +
              (pe[1][0] + pe[1][1] + pe[1][2] + pe[1][3]);
    U8 t;
    t.w[0] = cvtpk(pe[0][0], pe[0][1]); t.w[1] = cvtpk(pe[0][2], pe[0][3]);
    t.w[2] = cvtpk(pe[1][0], pe[1][1]); t.w[3] = cvtpk(pe[1][2], pe[1][3]);
    pa[f] = t.v;
  }
  // PV: one K=32 MFMA per (qfrag, ch-group); V B-frag from this wave's key-half cols
  const u16* vt0 = Vt[CUR];
  __builtin_amdgcn_s_setprio(1);
#pragma unroll
  for (int nt = 0; nt < 4; ++nt) {
    bf16x8 vF = *(const bf16x8*)(vt0 + (nt * 16 + l15) * 64 + vcol);
    oacc[0][nt] = mfma16(pa[0], vF, oacc[0][nt]);
    oacc[1][nt] = mfma16(pa[1], vF, oacc[1][nt]);
    oacc[2][nt] = mfma16(pa[2], vF, oacc[2][nt]);
    oacc[3][nt] = mfma16(pa[3], vF, oacc[3][nt]);
  }
  __builtin_amdgcn_s_setprio(0);
  // stage K(kt+1), V(kt+1) into other buffer (readers finished at previous barrier)
  if (pref) {
    u16* kd = (u16*)Ks[CUR ^ 1];
    *(u16x8*)(kd + kdst) = kr0;
    *(u16x8*)(kd + kdst + 2048) = kr1;
    u16* vd = (u16*)Vt[CUR ^ 1];
#pragma unroll
    for (int c = 0; c < 8; ++c) {
      u32 pk2 = (u32)va[c] | ((u32)vq[c] << 16);
      *(u32*)&vd[(chbase + c) * 64 + (pcol ^ (c << 3))] = pk2;
    }
  }
  __syncthreads();
}

// donate q-half (o0,o1 = its two 16-row frags) to LDS; static indices after inlining
__device__ __forceinline__ void donate2(float* Rw, float* Lxp,
                                        const f32x4 (&o0)[4], const f32x4 (&o1)[4],
                                        float l0, float l1, int quad, int l15) {
#pragma unroll
  for (int nt = 0; nt < 4; ++nt)
#pragma unroll
    for (int r = 0; r < 4; ++r) {
      Rw[(quad * 4 + r) * 64 + nt * 16 + l15] = o0[nt][r];
      Rw[(16 + quad * 4 + r) * 64 + nt * 16 + l15] = o1[nt][r];
    }
  if (quad == 0) { Lxp[l15] = l0; Lxp[16 + l15] = l1; }
}

__device__ __forceinline__ void epi2(const float* Rr, const float* Lxp,
                                     const f32x4 (&o0)[4], const f32x4 (&o1)[4],
                                     float l0, float l1, const float (&vsg)[4],
                                     float* __restrict__ out, int sqbase, int b, int h,
                                     int quad, int l15) {
#pragma unroll
  for (int ff = 0; ff < 2; ++ff) {
    float lt = (ff == 0 ? l0 : l1) + Lxp[ff * 16 + l15];
#pragma unroll
    for (int r = 0; r < 4; ++r) {
      int sq = sqbase + ff * 16 + quad * 4 + r;
      float inv = 1.0f / __shfl(lt, quad * 4 + r);
      float* orow = out + ((size_t)sq * 2 + b) * 1024 + h * 64;
#pragma unroll
      for (int nt = 0; nt < 4; ++nt) {
        float own = (ff == 0 ? o0[nt][r] : o1[nt][r]);
        orow[nt * 16 + l15] =
            (own + Rr[(ff * 16 + quad * 4 + r) * 64 + nt * 16 + l15]) * inv * vsg[nt];
      }
    }
  }
}

__global__ __launch_bounds__(256, 2) void k_attn(const u16* __restrict__ qatt,
                                                 const u16* __restrict__ key,
                                                 const u16* __restrict__ value,
                                                 const float* __restrict__ hbuf,
                                                 float* __restrict__ out) {
  int bh = blockIdx.x & 31;
  int qt = blockIdx.x >> 5;
  int b = bh >> 4, h = bh & 15;
  int tid = threadIdx.x, wave = tid >> 6, lane = tid & 63;
  int l15 = lane & 15, quad = lane >> 4;
  int qh = wave >> 1, kh = wave & 1;
  int q0 = qt * 128;

  __shared__ __align__(16) u16 Ks[2][64 * 64];   // [buf][key][ch], XOR-swizzled 128B rows
  __shared__ __align__(16) u16 Vt[2][64 * 64];   // [buf][ch][pi(key)], XOR-swizzled 128B rows
  __shared__ float Lx[2][2][32];                 // [qh][half][qlocal] l partials

  // Q B-frags: 4 qfrags x 2 ch-chunks; qrow = q0 + qh*64 + f*16 + l15
  bf16x8 qf[4][2];
#pragma unroll
  for (int f = 0; f < 4; ++f) {
    const u16* qrow = qatt + ((size_t)bh * 2048 + q0 + qh * 64 + f * 16 + l15) * 64 + quad * 8;
    qf[f][0] = *(const bf16x8*)qrow;
    qf[f][1] = *(const bf16x8*)(qrow + 32);
  }

  const u16* kb = key + (size_t)b * 1024 + (size_t)h * 64;
  const u16* vb = value + (size_t)b * 1024 + (size_t)h * 64;

  // K staging: thread t covers rows {t>>3, 32+(t>>3)}, ch chunk (t&7)*8
  int krow = tid >> 3;
  int kchk = (tid & 7) * 8;
  const u16* kp = kb + (size_t)krow * 2048 + kchk;
  int kdst = krow * 64 + (kchk ^ ((krow & 7) << 3));

  // V staging: lane covers keys 2p,2p+1 (p=lane&31), 8 ch at chbase; scatter col = pi(2p)
  int p = lane & 31;
  int chbase = wave * 16 + (lane >> 5) * 8;
  const u16* vp = vb + (size_t)2 * p * 2048 + chbase;
  int kk = 2 * p;
  int pcol = ((kk >> 5) & 1) * 32 + ((kk >> 2) & 3) * 8 + ((kk >> 4) & 1) * 4 + (kk & 3);
  int swr = (l15 & 7) << 3;                 // read-side row swizzle (u16 units)
  int kcolA = (8 * quad) ^ swr;             // K ch-chunk 0
  int kcolB = (32 + 8 * quad) ^ swr;        // K ch-chunk 1
  int vcol = (kh * 32 + 8 * quad) ^ swr;    // V key-half cols

  // prologue: K(0) into Ks[0], V(0) into Vt[0]
  {
    u16x8 kr0 = *(const u16x8*)kp;
    u16x8 kr1 = *(const u16x8*)(kp + (size_t)32 * 2048);
    *(u16x8*)(&Ks[0][kdst]) = kr0;
    *(u16x8*)(&Ks[0][kdst + 2048]) = kr1;
    u16x8 va = *(const u16x8*)vp;
    u16x8 vq = *(const u16x8*)(vp + 2048);
#pragma unroll
    for (int c = 0; c < 8; ++c) {
      u32 pk2 = (u32)va[c] | ((u32)vq[c] << 16);
      *(u32*)&Vt[0][(chbase + c) * 64 + (pcol ^ (c << 3))] = pk2;
    }
  }
  __syncthreads();

  f32x4 oacc[4][4] = {};
  float l_i[4] = {};

  for (int kt = 0; kt < 32; kt += 2) {
    attn_iter<0>(true, qf, kp, vp, Ks, Vt, oacc, l_i, kdst, chbase, pcol, l15, kh, kcolA, kcolB, vcol);
    attn_iter<1>(kt < 30, qf, kp, vp, Ks, Vt, oacc, l_i, kdst, chbase, pcol, l15, kh, kcolA, kcolB, vcol);
  }

  // quad-reduce l (lane holds partial for qrow=l15 over this wave's keys)
#pragma unroll
  for (int f = 0; f < 4; ++f) {
    float l = l_i[f];
    l += __shfl_xor(l, 16);
    l += __shfl_xor(l, 32);
    l_i[f] = l;
  }
  // cross-pair O reduction: wave (qh,kh) donates q-half (kh^1), keeps half kh.
  // Wave-uniform branches on kh keep all oacc indices STATIC (rule #20).
  float* base = (qh == 0) ? (float*)&Ks[0][0] : (float*)&Vt[0][0];
  if (kh == 0) {
    donate2(base + 2048, &Lx[qh][1][0], oacc[2], oacc[3], l_i[2], l_i[3], quad, l15);
  } else {
    donate2(base, &Lx[qh][0][0], oacc[0], oacc[1], l_i[0], l_i[1], quad, l15);
  }
  __syncthreads();
  // vsig inline (h holds MLP pre-activations: c = h[ch], f = h[1024+ch])
  float vsg[4];
#pragma unroll
  for (int nt = 0; nt < 4; ++nt) {
    int ch = h * 64 + nt * 16 + l15;
    vsg[nt] = sigm(hbuf[1024 + ch]) * tanhf(hbuf[ch]);
  }
  // epilogue: own half = partner's donated region + own oacc; /l, *vsig, write (s,b,H) fp32
  int sqbase = q0 + qh * 64 + kh * 32;
  if (kh == 0) {
    epi2(base, &Lx[qh][0][0], oacc[0], oacc[1], l_i[0], l_i[1], vsg, out, sqbase, b, h, quad, l15);
  } else {
    epi2(base + 2048, &Lx[qh][1][0], oacc[2], oacc[3], l_i[2], l_i[3], vsg, out, sqbase, b, h, quad, l15);
  }
}

extern "C" void kernel_launch(void* const* d_in, const int* in_sizes, int n_in,
                              void* d_out, int out_size, void* d_ws, size_t ws_size,
                              hipStream_t stream) {
  (void)in_sizes; (void)n_in; (void)out_size; (void)ws_size;
  const float* query = (const float*)d_in[0];
  const float* key   = (const float*)d_in[1];
  const float* value = (const float*)d_in[2];
  const float* qs    = (const float*)d_in[3];
  const float* ksp   = (const float*)d_in[4];
  const float* vs    = (const float*)d_in[5];
  const float* vq_w  = (const float*)d_in[6];
  const float* vq_b  = (const float*)d_in[7];
  const float* ql_w  = (const float*)d_in[8];
  const float* ql_b  = (const float*)d_in[9];
  const float* ln_g  = (const float*)d_in[10];
  const float* ln_b  = (const float*)d_in[11];
  float* out = (float*)d_out;

  float* ws = (float*)d_ws;
  float* h    = ws;                                 // 2048 f32
  float* gate = ws + 2048;                          // 1024 f32
  u16* qpre  = (u16*)(ws + 4096);                   // 2 x 4096x1024 bf16 (16 MB)
  u16* qbf   = qpre + (size_t)2 * 4096 * 1024;      // query bf16 (16 MB); qatt aliases
  u16* qatt  = qbf;                                 // 32x2048x64 bf16 (ln writes after gemm reads)
  u16* wbf   = qbf + (size_t)4096 * 2048;           // ql_w bf16 (4 MB)
  u16* kbf   = wbf + (size_t)1024 * 2048;           // key bf16 (8 MB)
  u16* vbf   = kbf + (size_t)4096 * 1024;           // value bf16 (8 MB)

  hipLaunchKernelGGL(k_cvt_h, dim3(2564), dim3(256), 0, stream,
                     (const float4*)query, (u16x4*)qbf,
                     (const float4*)ql_w,  (u16x4*)wbf,
                     (const float4*)key,   (u16x4*)kbf,
                     (const float4*)value, (u16x4*)vbf,
                     vs, vq_w, vq_b, h, qs, ksp, gate);
  hipLaunchKernelGGL(k_gemm, dim3(1024), dim3(256), 0, stream, qbf, wbf, qpre);
  hipLaunchKernelGGL(k_ln,   dim3(1024), dim3(256), 0, stream, qpre, qpre + (size_t)4096 * 1024,
                     ql_b, ln_g, ln_b, gate, qatt);
  hipLaunchKernelGGL(k_attn, dim3(512),  dim3(256), 0, stream, qatt, kbf, vbf, h, out);
}